// Round 1
// baseline (696.345 us; speedup 1.0000x reference)
//
#include <hip/hip_runtime.h>

#define N_NODES 100000
#define N_EDGES 400000
#define HALF_E  200000
#define BN_EPS  1e-5f

// K layout: 3 segments of 224 (200 real + 24 zero pad), total 672 = 21*32
// N (output cols) padded 200 -> 208 = 13*16
#define KSEG   224
#define KTOT   672
#define NPAD   208
#define CHUNKS 21

typedef __bf16 bf16x8 __attribute__((ext_vector_type(8)));
typedef float  f32x4  __attribute__((ext_vector_type(4)));

// ---- workspace layout (bytes) ----
#define A_OFF      0ull                 // N*400 f32 = 160,000,000 B
#define COLSUM_OFF 160000000ull         // 200 f32
#define COLSQ_OFF  160000800ull         // 200 f32
#define ZERO_BYTES 160001600ull
#define SCALE_OFF  160001600ull         // 200 f32
#define SHIFT_OFF  160002400ull         // 200 f32
#define WT_OFF     160003200ull         // 208*672 bf16 = 279,552 B (16B aligned)

static __device__ __forceinline__ unsigned short f2bf(float f) {
    union { float f; unsigned u; } v; v.f = f;
    unsigned u = v.u;
    unsigned r = (u + 0x7fffu + ((u >> 16) & 1u)) >> 16;  // RNE
    return (unsigned short)r;
}

// ---- pack Wt[n][k] = W_seg[k%224][n] (loop_rel folded into loop_w), bf16 ----
__global__ __launch_bounds__(256) void pack_wt(
    const float* __restrict__ in_w, const float* __restrict__ out_w,
    const float* __restrict__ loop_w, const float* __restrict__ loop_rel,
    unsigned short* __restrict__ Wt) {
    int idx = blockIdx.x * 256 + threadIdx.x;      // 546*256 == 208*672 exactly
    int n = idx / KTOT, k = idx - n * KTOT;
    int seg = k / KSEG, off = k - seg * KSEG;
    float v = 0.f;
    if (off < 200 && n < 200) {
        if (seg == 0)      v = in_w[off * 200 + n];
        else if (seg == 1) v = out_w[off * 200 + n];
        else               v = loop_w[off * 200 + n] * loop_rel[off];
    }
    Wt[idx] = f2bf(v);
}

// ---- edge scatter: one wave per edge, A[dst][seg*200 + d] += norm*x[src][d]*rel[t][d]
__global__ __launch_bounds__(256) void scatter_edges(
    const float* __restrict__ x, const float* __restrict__ rel,
    const float* __restrict__ norm, const int* __restrict__ esrc,
    const int* __restrict__ edst, const int* __restrict__ etyp,
    float* __restrict__ A) {
    int e = blockIdx.x * 4 + (threadIdx.x >> 6);   // grid = 100000 blocks -> 400000 waves
    int lane = threadIdx.x & 63;
    int src = esrc[e], dst = edst[e], t = etyp[e];
    float nv = norm[e];
    const float* xr = x + src * 200;
    const float* rr = rel + t * 200;
    float* ar = A + dst * 400 + (e < HALF_E ? 0 : 200);
#pragma unroll
    for (int i = 0; i < 4; ++i) {
        int d = lane + i * 64;
        if (d < 200) unsafeAtomicAdd(ar + d, xr[d] * rr[d] * nv);
    }
}

// ---- GEMM: h_pre[v][n] = B[v][:] . Wt[n][:] / 3 ; B = [A_in|A_out|x] with zero pads
__global__ __launch_bounds__(256) void gemm_nodes(
    const float* __restrict__ A, const float* __restrict__ x,
    const unsigned short* __restrict__ Wt, float* __restrict__ out) {
    __shared__ unsigned short Alds[128 * 32];
    __shared__ unsigned short Blds[NPAD * 32];
    int tid = threadIdx.x;
    int wave = tid >> 6, lane = tid & 63;
    int quad = lane >> 4, l15 = lane & 15;
    int row0 = blockIdx.x * 128;
    int ar = tid >> 3;            // 0..31 staging row within pass
    int col4 = (tid & 7) * 4;     // 0,4,...,28

    f32x4 acc[2][13];
#pragma unroll
    for (int i = 0; i < 2; ++i)
#pragma unroll
        for (int j = 0; j < 13; ++j) {
            acc[i][j].x = 0.f; acc[i][j].y = 0.f; acc[i][j].z = 0.f; acc[i][j].w = 0.f;
        }

    for (int chunk = 0; chunk < CHUNKS; ++chunk) {
        int seg = chunk / 7;
        int off0 = (chunk - seg * 7) * 32;          // 0..192
        int width = (off0 == 192) ? 8 : 32;         // real values in this chunk
        bool cv = (col4 < width);
        // stage A-tile (f32 -> bf16)
#pragma unroll
        for (int p = 0; p < 4; ++p) {
            int r = p * 32 + ar;
            int v = row0 + r;
            float4 val = make_float4(0.f, 0.f, 0.f, 0.f);
            if (v < N_NODES && cv) {
                const float* gp = (seg < 2) ? (A + v * 400 + seg * 200 + off0 + col4)
                                            : (x + v * 200 + off0 + col4);
                val = *reinterpret_cast<const float4*>(gp);
            }
            unsigned short* dp = Alds + r * 32 + col4;
            dp[0] = f2bf(val.x); dp[1] = f2bf(val.y);
            dp[2] = f2bf(val.z); dp[3] = f2bf(val.w);
        }
        // stage W-tile (already bf16): thread = n row, copy 32 shorts = 64B
        if (tid < NPAD) {
            const uint4* sp = reinterpret_cast<const uint4*>(Wt + tid * KTOT + chunk * 32);
            uint4* dp = reinterpret_cast<uint4*>(Blds + tid * 32);
            dp[0] = sp[0]; dp[1] = sp[1]; dp[2] = sp[2]; dp[3] = sp[3];
        }
        __syncthreads();
        // MFMA: wave covers m-tiles {2*wave, 2*wave+1} x all 13 n-tiles
        bf16x8 a0 = *reinterpret_cast<const bf16x8*>(Alds + ((wave * 2 + 0) * 16 + l15) * 32 + quad * 8);
        bf16x8 a1 = *reinterpret_cast<const bf16x8*>(Alds + ((wave * 2 + 1) * 16 + l15) * 32 + quad * 8);
#pragma unroll
        for (int nt = 0; nt < 13; ++nt) {
            bf16x8 b = *reinterpret_cast<const bf16x8*>(Blds + (nt * 16 + l15) * 32 + quad * 8);
            acc[0][nt] = __builtin_amdgcn_mfma_f32_16x16x32_bf16(a0, b, acc[0][nt], 0, 0, 0);
            acc[1][nt] = __builtin_amdgcn_mfma_f32_16x16x32_bf16(a1, b, acc[1][nt], 0, 0, 0);
        }
        __syncthreads();
    }
    // epilogue: D row = quad*4 + r, col = l15 ; scale by 1/3
#pragma unroll
    for (int i = 0; i < 2; ++i) {
        int mbase = row0 + (wave * 2 + i) * 16 + quad * 4;
#pragma unroll
        for (int nt = 0; nt < 13; ++nt) {
            int n = nt * 16 + l15;
            if (n < 200) {
#pragma unroll
                for (int r = 0; r < 4; ++r) {
                    int m = mbase + r;
                    if (m < N_NODES) out[m * 200 + n] = acc[i][nt][r] * (1.f / 3.f);
                }
            }
        }
    }
}

// ---- BN column stats: wave per row slice, lane owns cols {lane, lane+64, lane+128, lane+192}
__global__ __launch_bounds__(256) void bn_stats(
    const float* __restrict__ h, float* __restrict__ colsum, float* __restrict__ colsq) {
    int gw = blockIdx.x * 4 + (threadIdx.x >> 6);
    int lane = threadIdx.x & 63;
    int nw = gridDim.x * 4;
    float s[4] = {0.f, 0.f, 0.f, 0.f}, q[4] = {0.f, 0.f, 0.f, 0.f};
    for (int row = gw; row < N_NODES; row += nw) {
        const float* hr = h + row * 200;
#pragma unroll
        for (int i = 0; i < 4; ++i) {
            int c = lane + i * 64;
            if (c < 200) { float v = hr[c]; s[i] += v; q[i] += v * v; }
        }
    }
#pragma unroll
    for (int i = 0; i < 4; ++i) {
        int c = lane + i * 64;
        if (c < 200) { unsafeAtomicAdd(colsum + c, s[i]); unsafeAtomicAdd(colsq + c, q[i]); }
    }
}

__global__ void bn_finalize(const float* __restrict__ colsum, const float* __restrict__ colsq,
                            const float* __restrict__ gamma, const float* __restrict__ beta,
                            float* __restrict__ scale, float* __restrict__ shift) {
    int c = threadIdx.x;
    if (c < 200) {
        float mean = colsum[c] * (1.f / N_NODES);
        float var = colsq[c] * (1.f / N_NODES) - mean * mean;
        float inv = rsqrtf(var + BN_EPS);
        float sc = inv * gamma[c];
        scale[c] = sc;
        shift[c] = beta[c] - mean * sc;
    }
}

__global__ __launch_bounds__(256) void bn_apply(
    float* __restrict__ h, const float* __restrict__ scale, const float* __restrict__ shift) {
    __shared__ float ssc[200], ssh[200];
    if (threadIdx.x < 200) { ssc[threadIdx.x] = scale[threadIdx.x]; ssh[threadIdx.x] = shift[threadIdx.x]; }
    __syncthreads();
    const int total4 = N_NODES * 200 / 4;  // 5,000,000 float4
    int stride = gridDim.x * blockDim.x;
    for (int i = blockIdx.x * blockDim.x + threadIdx.x; i < total4; i += stride) {
        int c = (i % 50) * 4;
        float4 v = reinterpret_cast<float4*>(h)[i];
        v.x = v.x * ssc[c + 0] + ssh[c + 0];
        v.y = v.y * ssc[c + 1] + ssh[c + 1];
        v.z = v.z * ssc[c + 2] + ssh[c + 2];
        v.w = v.w * ssc[c + 3] + ssh[c + 3];
        reinterpret_cast<float4*>(h)[i] = v;
    }
}

// ---- rel_out = rel_repr @ w_rel (200x200 @ 200x200), fp32 exact ----
__global__ __launch_bounds__(256) void rel_out_k(
    const float* __restrict__ rel, const float* __restrict__ w, float* __restrict__ out) {
    int i = blockIdx.x, j = threadIdx.x;
    if (j < 200) {
        float acc = 0.f;
        for (int k = 0; k < 200; ++k) acc += rel[i * 200 + k] * w[k * 200 + j];
        out[i * 200 + j] = acc;
    }
}

extern "C" void kernel_launch(void* const* d_in, const int* in_sizes, int n_in,
                              void* d_out, int out_size, void* d_ws, size_t ws_size,
                              hipStream_t stream) {
    const float* x         = (const float*)d_in[0];
    const float* rel_repr  = (const float*)d_in[1];
    const float* edge_norm = (const float*)d_in[2];
    const float* in_w      = (const float*)d_in[3];
    const float* out_w     = (const float*)d_in[4];
    const float* loop_w    = (const float*)d_in[5];
    const float* loop_rel  = (const float*)d_in[6];
    const float* w_rel     = (const float*)d_in[7];
    const float* bn_gamma  = (const float*)d_in[8];
    const float* bn_beta   = (const float*)d_in[9];
    const int* edge_src    = (const int*)d_in[10];
    const int* edge_dst    = (const int*)d_in[11];
    const int* edge_type   = (const int*)d_in[12];

    float* out = (float*)d_out;
    char* ws = (char*)d_ws;
    float* A       = (float*)(ws + A_OFF);
    float* colsum  = (float*)(ws + COLSUM_OFF);
    float* colsq   = (float*)(ws + COLSQ_OFF);
    float* scale   = (float*)(ws + SCALE_OFF);
    float* shift   = (float*)(ws + SHIFT_OFF);
    unsigned short* Wt = (unsigned short*)(ws + WT_OFF);

    hipMemsetAsync(ws, 0, ZERO_BYTES, stream);                       // zero A + colsum/colsq
    pack_wt<<<546, 256, 0, stream>>>(in_w, out_w, loop_w, loop_rel, Wt);
    scatter_edges<<<N_EDGES / 4, 256, 0, stream>>>(x, rel_repr, edge_norm,
                                                   edge_src, edge_dst, edge_type, A);
    gemm_nodes<<<782, 256, 0, stream>>>(A, x, Wt, out);
    bn_stats<<<256, 256, 0, stream>>>(out, colsum, colsq);
    bn_finalize<<<1, 256, 0, stream>>>(colsum, colsq, bn_gamma, bn_beta, scale, shift);
    bn_apply<<<1024, 256, 0, stream>>>(out, scale, shift);
    rel_out_k<<<200, 256, 0, stream>>>(rel_repr, w_rel, out + 20000000);
}

// Round 2
// 624.506 us; speedup vs baseline: 1.1150x; 1.1150x over previous
//
#include <hip/hip_runtime.h>

#define N_NODES 100000
#define N_EDGES 400000
#define HALF_E  200000
#define BN_EPS  1e-5f

// A_bf layout per node row: [in 200 | out 200 | x 200 | pad 40] = 640 bf16
#define KTOT   640
#define CHUNKS 20
#define NPAD   208
#define ASTR   40      // LDS tile stride in bf16 (80 B -> 2-way bank aliasing = free)

typedef __bf16 bf16x8 __attribute__((ext_vector_type(8)));
typedef float  f32x4  __attribute__((ext_vector_type(4)));

// ---- workspace layout (bytes) ----
#define A_OFF      0ull                  // 100000*640*2 = 128,000,000
#define WT_OFF     128000000ull          // 208*640*2 = 266,240
#define HIST_OFF   128266240ull          // 100000*4
#define CURSOR_OFF 128666240ull          // 100000*4
#define COLSUM_OFF 129066240ull          // 200*4
#define COLSQ_OFF  129067040ull          // 200*4
#define ZERO_BASE  HIST_OFF
#define ZERO_BYTES 801600ull             // hist+cursor+colsum+colsq contiguous
#define SCALE_OFF  129067840ull
#define SHIFT_OFF  129068640ull
#define ROWPTR_OFF 129069440ull          // 100001*4 -> 400,016
#define BSUM_OFF   129469456ull          // 98*4
#define BOFF_OFF   129469848ull          // 98*4
#define EIDX_OFF   129470240ull          // 400000*4

#define SCAN_NBLK 98                     // 98*1024 >= 100000

static __device__ __forceinline__ unsigned short f2bf(float f) {
    union { float f; unsigned u; } v; v.f = f;
    unsigned u = v.u;
    unsigned r = (u + 0x7fffu + ((u >> 16) & 1u)) >> 16;  // RNE
    return (unsigned short)r;
}

// ---- pack Wt[n][k], k-layout [in|out|loop*loop_rel|pad], bf16 ----
__global__ __launch_bounds__(256) void pack_wt(
    const float* __restrict__ in_w, const float* __restrict__ out_w,
    const float* __restrict__ loop_w, const float* __restrict__ loop_rel,
    unsigned short* __restrict__ Wt) {
    int idx = blockIdx.x * 256 + threadIdx.x;      // 520*256 == 208*640
    int n = idx / KTOT, k = idx - n * KTOT;
    float v = 0.f;
    if (n < 200) {
        if (k < 200)       v = in_w[k * 200 + n];
        else if (k < 400)  v = out_w[(k - 200) * 200 + n];
        else if (k < 600)  v = loop_w[(k - 400) * 200 + n] * loop_rel[k - 400];
    }
    Wt[idx] = f2bf(v);
}

// ---- CSR build: histogram by dst ----
__global__ __launch_bounds__(256) void hist_k(const int* __restrict__ edst,
                                              unsigned* __restrict__ hist) {
    int e = blockIdx.x * 256 + threadIdx.x;
    if (e < N_EDGES) atomicAdd(&hist[edst[e]], 1u);
}

// ---- scan pass 1: per-block sums ----
__global__ __launch_bounds__(1024) void scan_part(const unsigned* __restrict__ hist,
                                                  unsigned* __restrict__ bsum) {
    __shared__ unsigned s[1024];
    int idx = blockIdx.x * 1024 + threadIdx.x;
    s[threadIdx.x] = (idx < N_NODES) ? hist[idx] : 0u;
    __syncthreads();
    for (int off = 512; off > 0; off >>= 1) {
        if (threadIdx.x < off) s[threadIdx.x] += s[threadIdx.x + off];
        __syncthreads();
    }
    if (threadIdx.x == 0) bsum[blockIdx.x] = s[0];
}

// ---- scan pass 2: serial exclusive scan of 98 block sums ----
__global__ void scan_top(const unsigned* __restrict__ bsum, unsigned* __restrict__ boff,
                         unsigned* __restrict__ rowptr) {
    if (threadIdx.x == 0) {
        unsigned run = 0;
        for (int b = 0; b < SCAN_NBLK; ++b) { boff[b] = run; run += bsum[b]; }
        rowptr[N_NODES] = N_EDGES;
    }
}

// ---- scan pass 3: intra-block exclusive scan + offset ----
__global__ __launch_bounds__(1024) void scan_low(const unsigned* __restrict__ hist,
                                                 const unsigned* __restrict__ boff,
                                                 unsigned* __restrict__ rowptr) {
    __shared__ unsigned s[1024];
    int idx = blockIdx.x * 1024 + threadIdx.x;
    unsigned own = (idx < N_NODES) ? hist[idx] : 0u;
    s[threadIdx.x] = own;
    __syncthreads();
    for (int off = 1; off < 1024; off <<= 1) {
        unsigned t = 0;
        if ((int)threadIdx.x >= off) t = s[threadIdx.x - off];
        __syncthreads();
        if ((int)threadIdx.x >= off) s[threadIdx.x] += t;
        __syncthreads();
    }
    if (idx < N_NODES) rowptr[idx] = boff[blockIdx.x] + s[threadIdx.x] - own;
}

// ---- CSR fill ----
__global__ __launch_bounds__(256) void fill_k(const int* __restrict__ edst,
                                              const unsigned* __restrict__ rowptr,
                                              unsigned* __restrict__ cursor,
                                              int* __restrict__ eidx) {
    int e = blockIdx.x * 256 + threadIdx.x;
    if (e < N_EDGES) {
        int d = edst[e];
        unsigned pos = rowptr[d] + atomicAdd(&cursor[d], 1u);
        eidx[pos] = e;
    }
}

// ---- gather aggregation: one wave per dst node, fp32 regs, write bf16 row once ----
__global__ __launch_bounds__(256) void aggregate(
    const float* __restrict__ x, const float* __restrict__ rel,
    const float* __restrict__ norm, const int* __restrict__ esrc,
    const int* __restrict__ etyp, const unsigned* __restrict__ rowptr,
    const int* __restrict__ eidx, unsigned short* __restrict__ A) {
    int v = blockIdx.x * 4 + (threadIdx.x >> 6);
    int lane = threadIdx.x & 63;
    float accI[4] = {0.f, 0.f, 0.f, 0.f}, accO[4] = {0.f, 0.f, 0.f, 0.f};
    int beg = rowptr[v], end = rowptr[v + 1];
    for (int j = beg; j < end; ++j) {
        int e = eidx[j];
        int src = esrc[e], t = etyp[e];
        float nv = norm[e];
        bool isIn = (e < HALF_E);
        const float* xr = x + src * 200;
        const float* rr = rel + t * 200;
#pragma unroll
        for (int i = 0; i < 4; ++i) {
            int d = lane + i * 64;
            if (d < 200) {
                float m = xr[d] * rr[d] * nv;
                if (isIn) accI[i] += m; else accO[i] += m;
            }
        }
    }
    unsigned short* ar = A + (size_t)v * KTOT;
    const float* xv = x + v * 200;
#pragma unroll
    for (int i = 0; i < 4; ++i) {
        int d = lane + i * 64;
        if (d < 200) {
            ar[d]       = f2bf(accI[i]);
            ar[200 + d] = f2bf(accO[i]);
            ar[400 + d] = f2bf(xv[d]);
        }
    }
    if (lane < 40) ar[600 + lane] = 0;
}

// ---- GEMM: out[v][n] = A_bf[v][:] . Wt[n][:] / 3 ; fused BN column stats ----
__global__ __launch_bounds__(256) void gemm_nodes(
    const unsigned short* __restrict__ A, const unsigned short* __restrict__ Wt,
    float* __restrict__ out, float* __restrict__ colsum, float* __restrict__ colsq) {
    __shared__ unsigned short Alds[128 * ASTR];
    __shared__ unsigned short Blds[NPAD * ASTR];
    int tid = threadIdx.x;
    int wave = tid >> 6, lane = tid & 63;
    int quad = lane >> 4, l15 = lane & 15;
    int row0 = blockIdx.x * 128;
    int srow = tid >> 2;            // 0..63 staging row within pass
    int scol = (tid & 3) * 8;       // bf16 col offset (16B granules)

    f32x4 acc[2][13];
#pragma unroll
    for (int i = 0; i < 2; ++i)
#pragma unroll
        for (int j = 0; j < 13; ++j) {
            acc[i][j].x = 0.f; acc[i][j].y = 0.f; acc[i][j].z = 0.f; acc[i][j].w = 0.f;
        }

    for (int chunk = 0; chunk < CHUNKS; ++chunk) {
        // stage A-tile: 128 rows x 32 bf16, uint4 copies
#pragma unroll
        for (int p = 0; p < 2; ++p) {
            int r = p * 64 + srow;
            int v = row0 + r;
            uint4 val = make_uint4(0u, 0u, 0u, 0u);
            if (v < N_NODES)
                val = *reinterpret_cast<const uint4*>(A + (size_t)v * KTOT + chunk * 32 + scol);
            *reinterpret_cast<uint4*>(Alds + r * ASTR + scol) = val;
        }
        // stage W-tile: row tid, 32 bf16
        if (tid < NPAD) {
            const uint4* sp = reinterpret_cast<const uint4*>(Wt + tid * KTOT + chunk * 32);
            uint4* dp = reinterpret_cast<uint4*>(Blds + tid * ASTR);
            dp[0] = sp[0]; dp[1] = sp[1]; dp[2] = sp[2]; dp[3] = sp[3];
        }
        __syncthreads();
        bf16x8 a0 = *reinterpret_cast<const bf16x8*>(Alds + ((wave * 2 + 0) * 16 + l15) * ASTR + quad * 8);
        bf16x8 a1 = *reinterpret_cast<const bf16x8*>(Alds + ((wave * 2 + 1) * 16 + l15) * ASTR + quad * 8);
#pragma unroll
        for (int nt = 0; nt < 13; ++nt) {
            bf16x8 b = *reinterpret_cast<const bf16x8*>(Blds + (nt * 16 + l15) * ASTR + quad * 8);
            acc[0][nt] = __builtin_amdgcn_mfma_f32_16x16x32_bf16(a0, b, acc[0][nt], 0, 0, 0);
            acc[1][nt] = __builtin_amdgcn_mfma_f32_16x16x32_bf16(a1, b, acc[1][nt], 0, 0, 0);
        }
        __syncthreads();
    }
    // epilogue: store /3, fused column sum/sumsq (rows >= N_NODES are zero)
#pragma unroll
    for (int nt = 0; nt < 13; ++nt) {
        int n = nt * 16 + l15;
        float s = 0.f, q = 0.f;
#pragma unroll
        for (int i = 0; i < 2; ++i) {
            int mbase = row0 + (wave * 2 + i) * 16 + quad * 4;
#pragma unroll
            for (int r = 0; r < 4; ++r) {
                float val = acc[i][nt][r] * (1.f / 3.f);
                int m = mbase + r;
                if (n < 200 && m < N_NODES) out[m * 200 + n] = val;
                s += val; q += val * val;
            }
        }
        s += __shfl_xor(s, 16); s += __shfl_xor(s, 32);
        q += __shfl_xor(q, 16); q += __shfl_xor(q, 32);
        if (lane < 16 && n < 200) {
            unsafeAtomicAdd(colsum + n, s);
            unsafeAtomicAdd(colsq + n, q);
        }
    }
}

__global__ void bn_finalize(const float* __restrict__ colsum, const float* __restrict__ colsq,
                            const float* __restrict__ gamma, const float* __restrict__ beta,
                            float* __restrict__ scale, float* __restrict__ shift) {
    int c = threadIdx.x;
    if (c < 200) {
        float mean = colsum[c] * (1.f / N_NODES);
        float var = colsq[c] * (1.f / N_NODES) - mean * mean;
        float inv = rsqrtf(var + BN_EPS);
        float sc = inv * gamma[c];
        scale[c] = sc;
        shift[c] = beta[c] - mean * sc;
    }
}

__global__ __launch_bounds__(256) void bn_apply(
    float* __restrict__ h, const float* __restrict__ scale, const float* __restrict__ shift) {
    __shared__ float ssc[200], ssh[200];
    if (threadIdx.x < 200) { ssc[threadIdx.x] = scale[threadIdx.x]; ssh[threadIdx.x] = shift[threadIdx.x]; }
    __syncthreads();
    const int total4 = N_NODES * 200 / 4;  // 5,000,000 float4
    int stride = gridDim.x * blockDim.x;
    for (int i = blockIdx.x * blockDim.x + threadIdx.x; i < total4; i += stride) {
        int c = (i % 50) * 4;
        float4 v = reinterpret_cast<float4*>(h)[i];
        v.x = v.x * ssc[c + 0] + ssh[c + 0];
        v.y = v.y * ssc[c + 1] + ssh[c + 1];
        v.z = v.z * ssc[c + 2] + ssh[c + 2];
        v.w = v.w * ssc[c + 3] + ssh[c + 3];
        reinterpret_cast<float4*>(h)[i] = v;
    }
}

// ---- rel_out = rel_repr @ w_rel (200x200 @ 200x200), fp32 exact ----
__global__ __launch_bounds__(256) void rel_out_k(
    const float* __restrict__ rel, const float* __restrict__ w, float* __restrict__ out) {
    int i = blockIdx.x, j = threadIdx.x;
    if (j < 200) {
        float acc = 0.f;
        for (int k = 0; k < 200; ++k) acc += rel[i * 200 + k] * w[k * 200 + j];
        out[i * 200 + j] = acc;
    }
}

extern "C" void kernel_launch(void* const* d_in, const int* in_sizes, int n_in,
                              void* d_out, int out_size, void* d_ws, size_t ws_size,
                              hipStream_t stream) {
    const float* x         = (const float*)d_in[0];
    const float* rel_repr  = (const float*)d_in[1];
    const float* edge_norm = (const float*)d_in[2];
    const float* in_w      = (const float*)d_in[3];
    const float* out_w     = (const float*)d_in[4];
    const float* loop_w    = (const float*)d_in[5];
    const float* loop_rel  = (const float*)d_in[6];
    const float* w_rel     = (const float*)d_in[7];
    const float* bn_gamma  = (const float*)d_in[8];
    const float* bn_beta   = (const float*)d_in[9];
    const int* edge_src    = (const int*)d_in[10];
    const int* edge_dst    = (const int*)d_in[11];
    const int* edge_type   = (const int*)d_in[12];

    float* out = (float*)d_out;
    char* ws = (char*)d_ws;
    unsigned short* A  = (unsigned short*)(ws + A_OFF);
    unsigned short* Wt = (unsigned short*)(ws + WT_OFF);
    unsigned* hist     = (unsigned*)(ws + HIST_OFF);
    unsigned* cursor   = (unsigned*)(ws + CURSOR_OFF);
    float* colsum      = (float*)(ws + COLSUM_OFF);
    float* colsq       = (float*)(ws + COLSQ_OFF);
    float* scale       = (float*)(ws + SCALE_OFF);
    float* shift       = (float*)(ws + SHIFT_OFF);
    unsigned* rowptr   = (unsigned*)(ws + ROWPTR_OFF);
    unsigned* bsum     = (unsigned*)(ws + BSUM_OFF);
    unsigned* boff     = (unsigned*)(ws + BOFF_OFF);
    int* eidx          = (int*)(ws + EIDX_OFF);

    hipMemsetAsync(ws + ZERO_BASE, 0, ZERO_BYTES, stream);  // hist+cursor+colsum+colsq
    pack_wt<<<520, 256, 0, stream>>>(in_w, out_w, loop_w, loop_rel, Wt);
    hist_k<<<1563, 256, 0, stream>>>(edge_dst, hist);
    scan_part<<<SCAN_NBLK, 1024, 0, stream>>>(hist, bsum);
    scan_top<<<1, 64, 0, stream>>>(bsum, boff, rowptr);
    scan_low<<<SCAN_NBLK, 1024, 0, stream>>>(hist, boff, rowptr);
    fill_k<<<1563, 256, 0, stream>>>(edge_dst, rowptr, cursor, eidx);
    aggregate<<<25000, 256, 0, stream>>>(x, rel_repr, edge_norm, edge_src, edge_type,
                                         rowptr, eidx, A);
    gemm_nodes<<<782, 256, 0, stream>>>(A, Wt, out, colsum, colsq);
    bn_finalize<<<1, 256, 0, stream>>>(colsum, colsq, bn_gamma, bn_beta, scale, shift);
    bn_apply<<<1024, 256, 0, stream>>>(out, scale, shift);
    rel_out_k<<<200, 256, 0, stream>>>(rel_repr, w_rel, out + 20000000);
}

// Round 3
// 454.481 us; speedup vs baseline: 1.5322x; 1.3741x over previous
//
#include <hip/hip_runtime.h>

#define N_NODES 100000
#define N_EDGES 400000
#define HALF_E  200000
#define BN_EPS  1e-5f

// A_bf layout per node row: [in 200 | out 200 | x 200 | pad 40] = 640 bf16
#define KTOT   640
#define CHUNKS 20
#define NPAD   208
#define ASTR   40      // LDS tile stride in bf16 (80 B -> 2-way bank aliasing = free)
#define GEMM_NBLK 782

typedef __bf16 bf16x8 __attribute__((ext_vector_type(8)));
typedef float  f32x4  __attribute__((ext_vector_type(4)));

// ---- workspace layout (bytes) ----
#define A_OFF      0ull                  // 100000*640*2 = 128,000,000
#define WT_OFF     128000000ull          // 208*640*2 = 266,240
#define HIST_OFF   128266240ull          // 100000*4
#define CURSOR_OFF 128666240ull          // 100000*4
#define ZERO_BASE  HIST_OFF
#define ZERO_BYTES 800000ull             // hist+cursor
#define SCALE_OFF  129066240ull          // 200*4
#define SHIFT_OFF  129067040ull          // 200*4
#define ROWPTR_OFF 129069440ull          // 100001*4
#define BSUM_OFF   129469856ull          // 98*4
#define BOFF_OFF   129470248ull          // 98*4
#define EIDX_OFF   129470640ull          // 400000*4 -> end 131,070,640
#define PS_OFF     131070640ull          // 782*200*4 = 625,600
#define PQ_OFF     131696240ull          // 782*200*4 -> end 132,321,840

#define SCAN_NBLK 98                     // 98*1024 >= 100000

static __device__ __forceinline__ unsigned short f2bf(float f) {
    union { float f; unsigned u; } v; v.f = f;
    unsigned u = v.u;
    unsigned r = (u + 0x7fffu + ((u >> 16) & 1u)) >> 16;  // RNE
    return (unsigned short)r;
}

// ---- pack Wt[n][k], k-layout [in|out|loop*loop_rel|pad], bf16 ----
__global__ __launch_bounds__(256) void pack_wt(
    const float* __restrict__ in_w, const float* __restrict__ out_w,
    const float* __restrict__ loop_w, const float* __restrict__ loop_rel,
    unsigned short* __restrict__ Wt) {
    int idx = blockIdx.x * 256 + threadIdx.x;      // 520*256 == 208*640
    int n = idx / KTOT, k = idx - n * KTOT;
    float v = 0.f;
    if (n < 200) {
        if (k < 200)       v = in_w[k * 200 + n];
        else if (k < 400)  v = out_w[(k - 200) * 200 + n];
        else if (k < 600)  v = loop_w[(k - 400) * 200 + n] * loop_rel[k - 400];
    }
    Wt[idx] = f2bf(v);
}

// ---- CSR build: histogram by dst ----
__global__ __launch_bounds__(256) void hist_k(const int* __restrict__ edst,
                                              unsigned* __restrict__ hist) {
    int e = blockIdx.x * 256 + threadIdx.x;
    if (e < N_EDGES) atomicAdd(&hist[edst[e]], 1u);
}

// ---- scan pass 1: per-block sums ----
__global__ __launch_bounds__(1024) void scan_part(const unsigned* __restrict__ hist,
                                                  unsigned* __restrict__ bsum) {
    __shared__ unsigned s[1024];
    int idx = blockIdx.x * 1024 + threadIdx.x;
    s[threadIdx.x] = (idx < N_NODES) ? hist[idx] : 0u;
    __syncthreads();
    for (int off = 512; off > 0; off >>= 1) {
        if (threadIdx.x < off) s[threadIdx.x] += s[threadIdx.x + off];
        __syncthreads();
    }
    if (threadIdx.x == 0) bsum[blockIdx.x] = s[0];
}

// ---- scan pass 2: serial exclusive scan of 98 block sums ----
__global__ void scan_top(const unsigned* __restrict__ bsum, unsigned* __restrict__ boff,
                         unsigned* __restrict__ rowptr) {
    if (threadIdx.x == 0) {
        unsigned run = 0;
        for (int b = 0; b < SCAN_NBLK; ++b) { boff[b] = run; run += bsum[b]; }
        rowptr[N_NODES] = N_EDGES;
    }
}

// ---- scan pass 3: intra-block exclusive scan + offset ----
__global__ __launch_bounds__(1024) void scan_low(const unsigned* __restrict__ hist,
                                                 const unsigned* __restrict__ boff,
                                                 unsigned* __restrict__ rowptr) {
    __shared__ unsigned s[1024];
    int idx = blockIdx.x * 1024 + threadIdx.x;
    unsigned own = (idx < N_NODES) ? hist[idx] : 0u;
    s[threadIdx.x] = own;
    __syncthreads();
    for (int off = 1; off < 1024; off <<= 1) {
        unsigned t = 0;
        if ((int)threadIdx.x >= off) t = s[threadIdx.x - off];
        __syncthreads();
        if ((int)threadIdx.x >= off) s[threadIdx.x] += t;
        __syncthreads();
    }
    if (idx < N_NODES) rowptr[idx] = boff[blockIdx.x] + s[threadIdx.x] - own;
}

// ---- CSR fill ----
__global__ __launch_bounds__(256) void fill_k(const int* __restrict__ edst,
                                              const unsigned* __restrict__ rowptr,
                                              unsigned* __restrict__ cursor,
                                              int* __restrict__ eidx) {
    int e = blockIdx.x * 256 + threadIdx.x;
    if (e < N_EDGES) {
        int d = edst[e];
        unsigned pos = rowptr[d] + atomicAdd(&cursor[d], 1u);
        eidx[pos] = e;
    }
}

// ---- gather aggregation: one wave per dst node, float4 lanes, write bf16 row once ----
__global__ __launch_bounds__(256) void aggregate(
    const float* __restrict__ x, const float* __restrict__ rel,
    const float* __restrict__ norm, const int* __restrict__ esrc,
    const int* __restrict__ etyp, const unsigned* __restrict__ rowptr,
    const int* __restrict__ eidx, unsigned short* __restrict__ A) {
    int v = blockIdx.x * 4 + (threadIdx.x >> 6);
    int lane = threadIdx.x & 63;
    bool act = lane < 50;                    // lane owns dims [lane*4, lane*4+4)
    float4 aI = make_float4(0.f, 0.f, 0.f, 0.f);
    float4 aO = make_float4(0.f, 0.f, 0.f, 0.f);
    int beg = rowptr[v], end = rowptr[v + 1];
    for (int j = beg; j < end; ++j) {
        int e = eidx[j];
        int src = esrc[e], t = etyp[e];
        float nv = norm[e];
        if (act) {
            float4 xr = *reinterpret_cast<const float4*>(x + src * 200 + lane * 4);
            float4 rr = *reinterpret_cast<const float4*>(rel + t * 200 + lane * 4);
            float4 m = make_float4(xr.x * rr.x * nv, xr.y * rr.y * nv,
                                   xr.z * rr.z * nv, xr.w * rr.w * nv);
            if (e < HALF_E) {
                aI.x += m.x; aI.y += m.y; aI.z += m.z; aI.w += m.w;
            } else {
                aO.x += m.x; aO.y += m.y; aO.z += m.z; aO.w += m.w;
            }
        }
    }
    unsigned short* ar = A + (size_t)v * KTOT;
    if (act) {
        float4 xv = *reinterpret_cast<const float4*>(x + v * 200 + lane * 4);
        ushort4 wI = make_ushort4(f2bf(aI.x), f2bf(aI.y), f2bf(aI.z), f2bf(aI.w));
        ushort4 wO = make_ushort4(f2bf(aO.x), f2bf(aO.y), f2bf(aO.z), f2bf(aO.w));
        ushort4 wX = make_ushort4(f2bf(xv.x), f2bf(xv.y), f2bf(xv.z), f2bf(xv.w));
        *reinterpret_cast<ushort4*>(ar + lane * 4)       = wI;
        *reinterpret_cast<ushort4*>(ar + 200 + lane * 4) = wO;
        *reinterpret_cast<ushort4*>(ar + 400 + lane * 4) = wX;
    }
    if (lane < 40) ar[600 + lane] = 0;
}

// ---- GEMM: out[v][n] = A_bf[v][:] . Wt[n][:] / 3 ; per-block BN partials (no atomics) ----
__global__ __launch_bounds__(256) void gemm_nodes(
    const unsigned short* __restrict__ A, const unsigned short* __restrict__ Wt,
    float* __restrict__ out, float* __restrict__ PS, float* __restrict__ PQ) {
    __shared__ unsigned short Alds[128 * ASTR];    // 10240 B, aliased as 2560 floats in epilogue
    __shared__ unsigned short Blds[NPAD * ASTR];
    int tid = threadIdx.x;
    int wave = tid >> 6, lane = tid & 63;
    int quad = lane >> 4, l15 = lane & 15;
    int row0 = blockIdx.x * 128;
    int srow = tid >> 2;            // 0..63 staging row within pass
    int scol = (tid & 3) * 8;       // bf16 col offset (16B granules)

    f32x4 acc[2][13];
#pragma unroll
    for (int i = 0; i < 2; ++i)
#pragma unroll
        for (int j = 0; j < 13; ++j) {
            acc[i][j].x = 0.f; acc[i][j].y = 0.f; acc[i][j].z = 0.f; acc[i][j].w = 0.f;
        }

    for (int chunk = 0; chunk < CHUNKS; ++chunk) {
        // stage A-tile: 128 rows x 32 bf16, uint4 copies
#pragma unroll
        for (int p = 0; p < 2; ++p) {
            int r = p * 64 + srow;
            int v = row0 + r;
            uint4 val = make_uint4(0u, 0u, 0u, 0u);
            if (v < N_NODES)
                val = *reinterpret_cast<const uint4*>(A + (size_t)v * KTOT + chunk * 32 + scol);
            *reinterpret_cast<uint4*>(Alds + r * ASTR + scol) = val;
        }
        // stage W-tile: row tid, 32 bf16
        if (tid < NPAD) {
            const uint4* sp = reinterpret_cast<const uint4*>(Wt + tid * KTOT + chunk * 32);
            uint4* dp = reinterpret_cast<uint4*>(Blds + tid * ASTR);
            dp[0] = sp[0]; dp[1] = sp[1]; dp[2] = sp[2]; dp[3] = sp[3];
        }
        __syncthreads();
        bf16x8 a0 = *reinterpret_cast<const bf16x8*>(Alds + ((wave * 2 + 0) * 16 + l15) * ASTR + quad * 8);
        bf16x8 a1 = *reinterpret_cast<const bf16x8*>(Alds + ((wave * 2 + 1) * 16 + l15) * ASTR + quad * 8);
#pragma unroll
        for (int nt = 0; nt < 13; ++nt) {
            bf16x8 b = *reinterpret_cast<const bf16x8*>(Blds + (nt * 16 + l15) * ASTR + quad * 8);
            acc[0][nt] = __builtin_amdgcn_mfma_f32_16x16x32_bf16(a0, b, acc[0][nt], 0, 0, 0);
            acc[1][nt] = __builtin_amdgcn_mfma_f32_16x16x32_bf16(a1, b, acc[1][nt], 0, 0, 0);
        }
        __syncthreads();
    }
    // epilogue: store /3; per-wave column stats -> LDS -> per-block partials (no atomics)
    float* redS = reinterpret_cast<float*>(Alds);        // [4][200]
    float* redQ = reinterpret_cast<float*>(Alds) + 800;  // [4][200]
#pragma unroll
    for (int nt = 0; nt < 13; ++nt) {
        int n = nt * 16 + l15;
        float s = 0.f, q = 0.f;
#pragma unroll
        for (int i = 0; i < 2; ++i) {
            int mbase = row0 + (wave * 2 + i) * 16 + quad * 4;
#pragma unroll
            for (int r = 0; r < 4; ++r) {
                float val = acc[i][nt][r] * (1.f / 3.f);
                int m = mbase + r;
                if (n < 200 && m < N_NODES) out[m * 200 + n] = val;
                s += val; q += val * val;
            }
        }
        s += __shfl_xor(s, 16); s += __shfl_xor(s, 32);
        q += __shfl_xor(q, 16); q += __shfl_xor(q, 32);
        if (lane < 16 && n < 200) {
            redS[wave * 200 + n] = s;
            redQ[wave * 200 + n] = q;
        }
    }
    __syncthreads();
    if (tid < 200) {
        float s = redS[tid] + redS[200 + tid] + redS[400 + tid] + redS[600 + tid];
        float q = redQ[tid] + redQ[200 + tid] + redQ[400 + tid] + redQ[600 + tid];
        PS[blockIdx.x * 200 + tid] = s;
        PQ[blockIdx.x * 200 + tid] = q;
    }
}

// ---- BN: reduce 782 partials per column, emit scale/shift. grid = 200 blocks ----
__global__ __launch_bounds__(256) void bn_reduce(
    const float* __restrict__ PS, const float* __restrict__ PQ,
    const float* __restrict__ gamma, const float* __restrict__ beta,
    float* __restrict__ scale, float* __restrict__ shift) {
    __shared__ float ls[256], lq[256];
    int c = blockIdx.x;
    float s = 0.f, q = 0.f;
    for (int b = threadIdx.x; b < GEMM_NBLK; b += 256) {
        s += PS[b * 200 + c];
        q += PQ[b * 200 + c];
    }
    ls[threadIdx.x] = s; lq[threadIdx.x] = q;
    __syncthreads();
    for (int off = 128; off > 0; off >>= 1) {
        if (threadIdx.x < off) {
            ls[threadIdx.x] += ls[threadIdx.x + off];
            lq[threadIdx.x] += lq[threadIdx.x + off];
        }
        __syncthreads();
    }
    if (threadIdx.x == 0) {
        float mean = ls[0] * (1.f / N_NODES);
        float var = lq[0] * (1.f / N_NODES) - mean * mean;
        float inv = rsqrtf(var + BN_EPS);
        float sc = inv * gamma[c];
        scale[c] = sc;
        shift[c] = beta[c] - mean * sc;
    }
}

__global__ __launch_bounds__(256) void bn_apply(
    float* __restrict__ h, const float* __restrict__ scale, const float* __restrict__ shift) {
    __shared__ float ssc[200], ssh[200];
    if (threadIdx.x < 200) { ssc[threadIdx.x] = scale[threadIdx.x]; ssh[threadIdx.x] = shift[threadIdx.x]; }
    __syncthreads();
    const int total4 = N_NODES * 200 / 4;  // 5,000,000 float4
    int stride = gridDim.x * blockDim.x;
    for (int i = blockIdx.x * blockDim.x + threadIdx.x; i < total4; i += stride) {
        int c = (i % 50) * 4;
        float4 v = reinterpret_cast<float4*>(h)[i];
        v.x = v.x * ssc[c + 0] + ssh[c + 0];
        v.y = v.y * ssc[c + 1] + ssh[c + 1];
        v.z = v.z * ssc[c + 2] + ssh[c + 2];
        v.w = v.w * ssc[c + 3] + ssh[c + 3];
        reinterpret_cast<float4*>(h)[i] = v;
    }
}

// ---- rel_out = rel_repr @ w_rel (200x200 @ 200x200), fp32 exact ----
__global__ __launch_bounds__(256) void rel_out_k(
    const float* __restrict__ rel, const float* __restrict__ w, float* __restrict__ out) {
    int i = blockIdx.x, j = threadIdx.x;
    if (j < 200) {
        float acc = 0.f;
        for (int k = 0; k < 200; ++k) acc += rel[i * 200 + k] * w[k * 200 + j];
        out[i * 200 + j] = acc;
    }
}

extern "C" void kernel_launch(void* const* d_in, const int* in_sizes, int n_in,
                              void* d_out, int out_size, void* d_ws, size_t ws_size,
                              hipStream_t stream) {
    const float* x         = (const float*)d_in[0];
    const float* rel_repr  = (const float*)d_in[1];
    const float* edge_norm = (const float*)d_in[2];
    const float* in_w      = (const float*)d_in[3];
    const float* out_w     = (const float*)d_in[4];
    const float* loop_w    = (const float*)d_in[5];
    const float* loop_rel  = (const float*)d_in[6];
    const float* w_rel     = (const float*)d_in[7];
    const float* bn_gamma  = (const float*)d_in[8];
    const float* bn_beta   = (const float*)d_in[9];
    const int* edge_src    = (const int*)d_in[10];
    const int* edge_dst    = (const int*)d_in[11];
    const int* edge_type   = (const int*)d_in[12];

    float* out = (float*)d_out;
    char* ws = (char*)d_ws;
    unsigned short* A  = (unsigned short*)(ws + A_OFF);
    unsigned short* Wt = (unsigned short*)(ws + WT_OFF);
    unsigned* hist     = (unsigned*)(ws + HIST_OFF);
    unsigned* cursor   = (unsigned*)(ws + CURSOR_OFF);
    float* scale       = (float*)(ws + SCALE_OFF);
    float* shift       = (float*)(ws + SHIFT_OFF);
    unsigned* rowptr   = (unsigned*)(ws + ROWPTR_OFF);
    unsigned* bsum     = (unsigned*)(ws + BSUM_OFF);
    unsigned* boff     = (unsigned*)(ws + BOFF_OFF);
    int* eidx          = (int*)(ws + EIDX_OFF);
    float* PS          = (float*)(ws + PS_OFF);
    float* PQ          = (float*)(ws + PQ_OFF);

    hipMemsetAsync(ws + ZERO_BASE, 0, ZERO_BYTES, stream);  // hist+cursor
    pack_wt<<<520, 256, 0, stream>>>(in_w, out_w, loop_w, loop_rel, Wt);
    hist_k<<<1563, 256, 0, stream>>>(edge_dst, hist);
    scan_part<<<SCAN_NBLK, 1024, 0, stream>>>(hist, bsum);
    scan_top<<<1, 64, 0, stream>>>(bsum, boff, rowptr);
    scan_low<<<SCAN_NBLK, 1024, 0, stream>>>(hist, boff, rowptr);
    fill_k<<<1563, 256, 0, stream>>>(edge_dst, rowptr, cursor, eidx);
    aggregate<<<25000, 256, 0, stream>>>(x, rel_repr, edge_norm, edge_src, edge_type,
                                         rowptr, eidx, A);
    gemm_nodes<<<GEMM_NBLK, 256, 0, stream>>>(A, Wt, out, PS, PQ);
    bn_reduce<<<200, 256, 0, stream>>>(PS, PQ, bn_gamma, bn_beta, scale, shift);
    bn_apply<<<1024, 256, 0, stream>>>(out, scale, shift);
    rel_out_k<<<200, 256, 0, stream>>>(rel_repr, w_rel, out + 20000000);
}

// Round 4
// 386.477 us; speedup vs baseline: 1.8018x; 1.1760x over previous
//
#include <hip/hip_runtime.h>

#define N_NODES 100000
#define N_EDGES 400000
#define HALF_E  200000
#define BN_EPS  1e-5f

// A_bf layout per node row: [in 200 | out 200 | x 200 | pad 40] = 640 bf16 (1280 B, 10 lines)
#define KTOT   640
#define CHUNKS 20
#define NPAD   208
#define ASTR   40      // LDS tile stride in bf16 (80 B -> 2-way bank aliasing = free)
#define GEMM_NBLK 782

typedef __bf16 bf16x8 __attribute__((ext_vector_type(8)));
typedef float  f32x4  __attribute__((ext_vector_type(4)));

// ---- workspace layout (bytes) ----
#define A_OFF      0ull                  // 100000*640*2 = 128,000,000
#define WT_OFF     128000000ull          // 208*640*2 = 266,240
#define HIST_OFF   128266240ull          // 100000*4
#define CURSOR_OFF 128666240ull          // 100000*4
#define ZERO_BASE  HIST_OFF
#define ZERO_BYTES 800000ull             // hist+cursor
#define SCALE_OFF  129066240ull          // 200*4
#define SHIFT_OFF  129067040ull          // 200*4
#define ROWPTR_OFF 129069440ull          // 100001*4
#define BSUM_OFF   129469856ull          // 98*4
#define BOFF_OFF   129470248ull          // 98*4
#define REC_OFF    129470640ull          // 400000*16 = 6,400,000 (16B aligned)
#define PS_OFF     135870640ull          // 782*200*4 = 625,600
#define PQ_OFF     136496240ull          // 782*200*4 -> end 137,121,840

#define SCAN_NBLK 98                     // 98*1024 >= 100000

static __device__ __forceinline__ unsigned short f2bf(float f) {
    union { float f; unsigned u; } v; v.f = f;
    unsigned u = v.u;
    unsigned r = (u + 0x7fffu + ((u >> 16) & 1u)) >> 16;  // RNE
    return (unsigned short)r;
}
static __device__ __forceinline__ float bf2f(unsigned short s) {
    union { unsigned u; float f; } v; v.u = ((unsigned)s) << 16; return v.f;
}

// ---- pack Wt[n][k], k-layout [in|out|loop*loop_rel|pad], bf16 ----
__global__ __launch_bounds__(256) void pack_wt(
    const float* __restrict__ in_w, const float* __restrict__ out_w,
    const float* __restrict__ loop_w, const float* __restrict__ loop_rel,
    unsigned short* __restrict__ Wt) {
    int idx = blockIdx.x * 256 + threadIdx.x;      // 520*256 == 208*640
    int n = idx / KTOT, k = idx - n * KTOT;
    float v = 0.f;
    if (n < 200) {
        if (k < 200)       v = in_w[k * 200 + n];
        else if (k < 400)  v = out_w[(k - 200) * 200 + n];
        else if (k < 600)  v = loop_w[(k - 400) * 200 + n] * loop_rel[k - 400];
    }
    Wt[idx] = f2bf(v);
}

// ---- write x-segment of A (bf16) + zero pad; also the gather source for aggregate ----
__global__ __launch_bounds__(256) void write_xseg(
    const float* __restrict__ x, unsigned short* __restrict__ A) {
    int v = blockIdx.x * 4 + (threadIdx.x >> 6);
    int lane = threadIdx.x & 63;
    unsigned short* ar = A + (size_t)v * KTOT;
    if (lane < 50) {
        float4 xv = *reinterpret_cast<const float4*>(x + v * 200 + lane * 4);
        ushort4 w = make_ushort4(f2bf(xv.x), f2bf(xv.y), f2bf(xv.z), f2bf(xv.w));
        *reinterpret_cast<ushort4*>(ar + 400 + lane * 4) = w;
    }
    if (lane < 40) ar[600 + lane] = 0;
}

// ---- CSR build: histogram by dst ----
__global__ __launch_bounds__(256) void hist_k(const int* __restrict__ edst,
                                              unsigned* __restrict__ hist) {
    int e = blockIdx.x * 256 + threadIdx.x;
    if (e < N_EDGES) atomicAdd(&hist[edst[e]], 1u);
}

// ---- scan pass 1: per-block sums ----
__global__ __launch_bounds__(1024) void scan_part(const unsigned* __restrict__ hist,
                                                  unsigned* __restrict__ bsum) {
    __shared__ unsigned s[1024];
    int idx = blockIdx.x * 1024 + threadIdx.x;
    s[threadIdx.x] = (idx < N_NODES) ? hist[idx] : 0u;
    __syncthreads();
    for (int off = 512; off > 0; off >>= 1) {
        if (threadIdx.x < off) s[threadIdx.x] += s[threadIdx.x + off];
        __syncthreads();
    }
    if (threadIdx.x == 0) bsum[blockIdx.x] = s[0];
}

// ---- scan pass 2: serial exclusive scan of 98 block sums ----
__global__ void scan_top(const unsigned* __restrict__ bsum, unsigned* __restrict__ boff,
                         unsigned* __restrict__ rowptr) {
    if (threadIdx.x == 0) {
        unsigned run = 0;
        for (int b = 0; b < SCAN_NBLK; ++b) { boff[b] = run; run += bsum[b]; }
        rowptr[N_NODES] = N_EDGES;
    }
}

// ---- scan pass 3: intra-block exclusive scan + offset ----
__global__ __launch_bounds__(1024) void scan_low(const unsigned* __restrict__ hist,
                                                 const unsigned* __restrict__ boff,
                                                 unsigned* __restrict__ rowptr) {
    __shared__ unsigned s[1024];
    int idx = blockIdx.x * 1024 + threadIdx.x;
    unsigned own = (idx < N_NODES) ? hist[idx] : 0u;
    s[threadIdx.x] = own;
    __syncthreads();
    for (int off = 1; off < 1024; off <<= 1) {
        unsigned t = 0;
        if ((int)threadIdx.x >= off) t = s[threadIdx.x - off];
        __syncthreads();
        if ((int)threadIdx.x >= off) s[threadIdx.x] += t;
        __syncthreads();
    }
    if (idx < N_NODES) rowptr[idx] = boff[blockIdx.x] + s[threadIdx.x] - own;
}

// ---- CSR fill: packed edge records {src, type, norm, dir} at sorted positions ----
__global__ __launch_bounds__(256) void fill_k(
    const int* __restrict__ edst, const int* __restrict__ esrc,
    const int* __restrict__ etyp, const float* __restrict__ norm,
    const unsigned* __restrict__ rowptr, unsigned* __restrict__ cursor,
    int4* __restrict__ recs) {
    int e = blockIdx.x * 256 + threadIdx.x;
    if (e < N_EDGES) {
        int d = edst[e];
        unsigned pos = rowptr[d] + atomicAdd(&cursor[d], 1u);
        recs[pos] = make_int4(esrc[e], etyp[e], __float_as_int(norm[e]), (e < HALF_E) ? 1 : 0);
    }
}

// ---- gather aggregation: one wave per dst node; bf16 x-rows from A's x-segment;
// ---- packed recs; 2 edges in flight per iteration ----
__global__ __launch_bounds__(256) void aggregate(
    const float* __restrict__ rel, const unsigned* __restrict__ rowptr,
    const int4* __restrict__ recs, unsigned short* __restrict__ A) {
    int v = blockIdx.x * 4 + (threadIdx.x >> 6);
    int lane = threadIdx.x & 63;
    bool act = lane < 50;                    // lane owns dims [lane*4, lane*4+4)
    int col = lane * 4;
    const unsigned short* Axs = A + 400;     // x-segment base
    float4 aI = make_float4(0.f, 0.f, 0.f, 0.f);
    float4 aO = make_float4(0.f, 0.f, 0.f, 0.f);
    int beg = rowptr[v], end = rowptr[v + 1];
    int j = beg;
    for (; j + 1 < end; j += 2) {
        int4 r0 = recs[j];
        int4 r1 = recs[j + 1];
        float n0 = __int_as_float(r0.z), n1 = __int_as_float(r1.z);
        if (act) {
            ushort4 x0 = *reinterpret_cast<const ushort4*>(Axs + (size_t)r0.x * KTOT + col);
            ushort4 x1 = *reinterpret_cast<const ushort4*>(Axs + (size_t)r1.x * KTOT + col);
            float4 rl0 = *reinterpret_cast<const float4*>(rel + r0.y * 200 + col);
            float4 rl1 = *reinterpret_cast<const float4*>(rel + r1.y * 200 + col);
            float4 m0 = make_float4(bf2f(x0.x) * rl0.x * n0, bf2f(x0.y) * rl0.y * n0,
                                    bf2f(x0.z) * rl0.z * n0, bf2f(x0.w) * rl0.w * n0);
            float4 m1 = make_float4(bf2f(x1.x) * rl1.x * n1, bf2f(x1.y) * rl1.y * n1,
                                    bf2f(x1.z) * rl1.z * n1, bf2f(x1.w) * rl1.w * n1);
            if (r0.w) { aI.x += m0.x; aI.y += m0.y; aI.z += m0.z; aI.w += m0.w; }
            else      { aO.x += m0.x; aO.y += m0.y; aO.z += m0.z; aO.w += m0.w; }
            if (r1.w) { aI.x += m1.x; aI.y += m1.y; aI.z += m1.z; aI.w += m1.w; }
            else      { aO.x += m1.x; aO.y += m1.y; aO.z += m1.z; aO.w += m1.w; }
        }
    }
    if (j < end) {
        int4 r0 = recs[j];
        float n0 = __int_as_float(r0.z);
        if (act) {
            ushort4 x0 = *reinterpret_cast<const ushort4*>(Axs + (size_t)r0.x * KTOT + col);
            float4 rl0 = *reinterpret_cast<const float4*>(rel + r0.y * 200 + col);
            float4 m0 = make_float4(bf2f(x0.x) * rl0.x * n0, bf2f(x0.y) * rl0.y * n0,
                                    bf2f(x0.z) * rl0.z * n0, bf2f(x0.w) * rl0.w * n0);
            if (r0.w) { aI.x += m0.x; aI.y += m0.y; aI.z += m0.z; aI.w += m0.w; }
            else      { aO.x += m0.x; aO.y += m0.y; aO.z += m0.z; aO.w += m0.w; }
        }
    }
    if (act) {
        unsigned short* ar = A + (size_t)v * KTOT;
        ushort4 wI = make_ushort4(f2bf(aI.x), f2bf(aI.y), f2bf(aI.z), f2bf(aI.w));
        ushort4 wO = make_ushort4(f2bf(aO.x), f2bf(aO.y), f2bf(aO.z), f2bf(aO.w));
        *reinterpret_cast<ushort4*>(ar + col)       = wI;
        *reinterpret_cast<ushort4*>(ar + 200 + col) = wO;
    }
}

// ---- GEMM: out[v][n] = A_bf[v][:] . Wt[n][:] / 3 ; per-block BN partials (no atomics) ----
__global__ __launch_bounds__(256) void gemm_nodes(
    const unsigned short* __restrict__ A, const unsigned short* __restrict__ Wt,
    float* __restrict__ out, float* __restrict__ PS, float* __restrict__ PQ) {
    __shared__ unsigned short Alds[128 * ASTR];    // 10240 B, aliased as floats in epilogue
    __shared__ unsigned short Blds[NPAD * ASTR];
    int tid = threadIdx.x;
    int wave = tid >> 6, lane = tid & 63;
    int quad = lane >> 4, l15 = lane & 15;
    int row0 = blockIdx.x * 128;
    int srow = tid >> 2;            // 0..63 staging row within pass
    int scol = (tid & 3) * 8;       // bf16 col offset (16B granules)

    f32x4 acc[2][13];
#pragma unroll
    for (int i = 0; i < 2; ++i)
#pragma unroll
        for (int j = 0; j < 13; ++j) {
            acc[i][j].x = 0.f; acc[i][j].y = 0.f; acc[i][j].z = 0.f; acc[i][j].w = 0.f;
        }

    for (int chunk = 0; chunk < CHUNKS; ++chunk) {
        // stage A-tile: 128 rows x 32 bf16, uint4 copies
#pragma unroll
        for (int p = 0; p < 2; ++p) {
            int r = p * 64 + srow;
            int v = row0 + r;
            uint4 val = make_uint4(0u, 0u, 0u, 0u);
            if (v < N_NODES)
                val = *reinterpret_cast<const uint4*>(A + (size_t)v * KTOT + chunk * 32 + scol);
            *reinterpret_cast<uint4*>(Alds + r * ASTR + scol) = val;
        }
        // stage W-tile: row tid, 32 bf16
        if (tid < NPAD) {
            const uint4* sp = reinterpret_cast<const uint4*>(Wt + tid * KTOT + chunk * 32);
            uint4* dp = reinterpret_cast<uint4*>(Blds + tid * ASTR);
            dp[0] = sp[0]; dp[1] = sp[1]; dp[2] = sp[2]; dp[3] = sp[3];
        }
        __syncthreads();
        bf16x8 a0 = *reinterpret_cast<const bf16x8*>(Alds + ((wave * 2 + 0) * 16 + l15) * ASTR + quad * 8);
        bf16x8 a1 = *reinterpret_cast<const bf16x8*>(Alds + ((wave * 2 + 1) * 16 + l15) * ASTR + quad * 8);
#pragma unroll
        for (int nt = 0; nt < 13; ++nt) {
            bf16x8 b = *reinterpret_cast<const bf16x8*>(Blds + (nt * 16 + l15) * ASTR + quad * 8);
            acc[0][nt] = __builtin_amdgcn_mfma_f32_16x16x32_bf16(a0, b, acc[0][nt], 0, 0, 0);
            acc[1][nt] = __builtin_amdgcn_mfma_f32_16x16x32_bf16(a1, b, acc[1][nt], 0, 0, 0);
        }
        __syncthreads();
    }
    // epilogue: store /3; per-wave column stats -> LDS -> per-block partials (no atomics)
    float* redS = reinterpret_cast<float*>(Alds);        // [4][200]
    float* redQ = reinterpret_cast<float*>(Alds) + 800;  // [4][200]
#pragma unroll
    for (int nt = 0; nt < 13; ++nt) {
        int n = nt * 16 + l15;
        float s = 0.f, q = 0.f;
#pragma unroll
        for (int i = 0; i < 2; ++i) {
            int mbase = row0 + (wave * 2 + i) * 16 + quad * 4;
#pragma unroll
            for (int r = 0; r < 4; ++r) {
                float val = acc[i][nt][r] * (1.f / 3.f);
                int m = mbase + r;
                if (n < 200 && m < N_NODES) out[m * 200 + n] = val;
                s += val; q += val * val;
            }
        }
        s += __shfl_xor(s, 16); s += __shfl_xor(s, 32);
        q += __shfl_xor(q, 16); q += __shfl_xor(q, 32);
        if (lane < 16 && n < 200) {
            redS[wave * 200 + n] = s;
            redQ[wave * 200 + n] = q;
        }
    }
    __syncthreads();
    if (tid < 200) {
        float s = redS[tid] + redS[200 + tid] + redS[400 + tid] + redS[600 + tid];
        float q = redQ[tid] + redQ[200 + tid] + redQ[400 + tid] + redQ[600 + tid];
        PS[blockIdx.x * 200 + tid] = s;
        PQ[blockIdx.x * 200 + tid] = q;
    }
}

// ---- BN: reduce 782 partials per column, emit scale/shift. grid = 200 blocks ----
__global__ __launch_bounds__(256) void bn_reduce(
    const float* __restrict__ PS, const float* __restrict__ PQ,
    const float* __restrict__ gamma, const float* __restrict__ beta,
    float* __restrict__ scale, float* __restrict__ shift) {
    __shared__ float ls[256], lq[256];
    int c = blockIdx.x;
    float s = 0.f, q = 0.f;
    for (int b = threadIdx.x; b < GEMM_NBLK; b += 256) {
        s += PS[b * 200 + c];
        q += PQ[b * 200 + c];
    }
    ls[threadIdx.x] = s; lq[threadIdx.x] = q;
    __syncthreads();
    for (int off = 128; off > 0; off >>= 1) {
        if (threadIdx.x < off) {
            ls[threadIdx.x] += ls[threadIdx.x + off];
            lq[threadIdx.x] += lq[threadIdx.x + off];
        }
        __syncthreads();
    }
    if (threadIdx.x == 0) {
        float mean = ls[0] * (1.f / N_NODES);
        float var = lq[0] * (1.f / N_NODES) - mean * mean;
        float inv = rsqrtf(var + BN_EPS);
        float sc = inv * gamma[c];
        scale[c] = sc;
        shift[c] = beta[c] - mean * sc;
    }
}

__global__ __launch_bounds__(256) void bn_apply(
    float* __restrict__ h, const float* __restrict__ scale, const float* __restrict__ shift) {
    __shared__ float ssc[200], ssh[200];
    if (threadIdx.x < 200) { ssc[threadIdx.x] = scale[threadIdx.x]; ssh[threadIdx.x] = shift[threadIdx.x]; }
    __syncthreads();
    const int total4 = N_NODES * 200 / 4;  // 5,000,000 float4
    int stride = gridDim.x * blockDim.x;
    for (int i = blockIdx.x * blockDim.x + threadIdx.x; i < total4; i += stride) {
        int c = (i % 50) * 4;
        float4 v = reinterpret_cast<float4*>(h)[i];
        v.x = v.x * ssc[c + 0] + ssh[c + 0];
        v.y = v.y * ssc[c + 1] + ssh[c + 1];
        v.z = v.z * ssc[c + 2] + ssh[c + 2];
        v.w = v.w * ssc[c + 3] + ssh[c + 3];
        reinterpret_cast<float4*>(h)[i] = v;
    }
}

// ---- rel_out = rel_repr @ w_rel (200x200 @ 200x200), fp32 exact ----
__global__ __launch_bounds__(256) void rel_out_k(
    const float* __restrict__ rel, const float* __restrict__ w, float* __restrict__ out) {
    int i = blockIdx.x, j = threadIdx.x;
    if (j < 200) {
        float acc = 0.f;
        for (int k = 0; k < 200; ++k) acc += rel[i * 200 + k] * w[k * 200 + j];
        out[i * 200 + j] = acc;
    }
}

extern "C" void kernel_launch(void* const* d_in, const int* in_sizes, int n_in,
                              void* d_out, int out_size, void* d_ws, size_t ws_size,
                              hipStream_t stream) {
    const float* x         = (const float*)d_in[0];
    const float* rel_repr  = (const float*)d_in[1];
    const float* edge_norm = (const float*)d_in[2];
    const float* in_w      = (const float*)d_in[3];
    const float* out_w     = (const float*)d_in[4];
    const float* loop_w    = (const float*)d_in[5];
    const float* loop_rel  = (const float*)d_in[6];
    const float* w_rel     = (const float*)d_in[7];
    const float* bn_gamma  = (const float*)d_in[8];
    const float* bn_beta   = (const float*)d_in[9];
    const int* edge_src    = (const int*)d_in[10];
    const int* edge_dst    = (const int*)d_in[11];
    const int* edge_type   = (const int*)d_in[12];

    float* out = (float*)d_out;
    char* ws = (char*)d_ws;
    unsigned short* A  = (unsigned short*)(ws + A_OFF);
    unsigned short* Wt = (unsigned short*)(ws + WT_OFF);
    unsigned* hist     = (unsigned*)(ws + HIST_OFF);
    unsigned* cursor   = (unsigned*)(ws + CURSOR_OFF);
    float* scale       = (float*)(ws + SCALE_OFF);
    float* shift       = (float*)(ws + SHIFT_OFF);
    unsigned* rowptr   = (unsigned*)(ws + ROWPTR_OFF);
    unsigned* bsum     = (unsigned*)(ws + BSUM_OFF);
    unsigned* boff     = (unsigned*)(ws + BOFF_OFF);
    int4* recs         = (int4*)(ws + REC_OFF);
    float* PS          = (float*)(ws + PS_OFF);
    float* PQ          = (float*)(ws + PQ_OFF);

    hipMemsetAsync(ws + ZERO_BASE, 0, ZERO_BYTES, stream);  // hist+cursor
    pack_wt<<<520, 256, 0, stream>>>(in_w, out_w, loop_w, loop_rel, Wt);
    write_xseg<<<25000, 256, 0, stream>>>(x, A);
    hist_k<<<1563, 256, 0, stream>>>(edge_dst, hist);
    scan_part<<<SCAN_NBLK, 1024, 0, stream>>>(hist, bsum);
    scan_top<<<1, 64, 0, stream>>>(bsum, boff, rowptr);
    scan_low<<<SCAN_NBLK, 1024, 0, stream>>>(hist, boff, rowptr);
    fill_k<<<1563, 256, 0, stream>>>(edge_dst, edge_src, edge_type, edge_norm,
                                     rowptr, cursor, recs);
    aggregate<<<25000, 256, 0, stream>>>(rel_repr, rowptr, recs, A);
    gemm_nodes<<<GEMM_NBLK, 256, 0, stream>>>(A, Wt, out, PS, PQ);
    bn_reduce<<<200, 256, 0, stream>>>(PS, PQ, bn_gamma, bn_beta, scale, shift);
    bn_apply<<<1024, 256, 0, stream>>>(out, scale, shift);
    rel_out_k<<<200, 256, 0, stream>>>(rel_repr, w_rel, out + 20000000);
}